// Round 2
// baseline (5022.058 us; speedup 1.0000x reference)
//
#include <hip/hip_runtime.h>

#define BB 256
#define NN 512
#define DD 128
#define HH 8
#define TN 64     // nodes per LDS tile
#define NT 8      // tiles (TN*NT == NN)

static constexpr float NEGC = -1e9f;
static constexpr float INV_SQRT_D = 0.08838834764831845f; // 1/sqrt(128)

// ---------------- precompute: fixed_ctx = mean_n(E) @ W_fixed ----------------
__global__ __launch_bounds__(128)
void precompute_fc(const float* __restrict__ E, const float* __restrict__ Wf,
                   float* __restrict__ fc) {
    int b = blockIdx.x, d = threadIdx.x;   // 128 threads
    __shared__ float ge[DD];
    const float* Eb = E + (size_t)b * NN * DD;
    float s = 0.f;
    for (int n = 0; n < NN; ++n) s += Eb[n * DD + d];
    ge[d] = s * (1.0f / 512.0f);
    __syncthreads();
    float o = 0.f;
    for (int k = 0; k < DD; ++k) o += ge[k] * Wf[k * DD + d];
    fc[b * DD + d] = o;
}

// ---- precompute: WkT[k][d] = W_node[d][k] (k<128);  W_og = W_out @ Wl^T ----
__global__ __launch_bounds__(128)
void precompute_w(const float* __restrict__ Wn, const float* __restrict__ Wout,
                  float* __restrict__ Wog, float* __restrict__ WkT) {
    int k = blockIdx.x, d = threadIdx.x;
    WkT[k * DD + d] = Wn[d * 384 + k];
    float s = 0.f;
    for (int e = 0; e < DD; ++e) s += Wout[k * DD + e] * Wn[d * 384 + 256 + e];
    Wog[k * DD + d] = s;
}

// ---------------------------- main decoder ----------------------------------
struct alignas(16) SM {
    float Et[TN][132];   // E tile, +4 pad -> conflict-free row & col access
    float qt[HH][132];   // q~ (0.25 folded), padded
    float eb[HH][132];   // normalized attn-weighted embedding
    float part[4][DD];   // partial-sum scratch for small matmuls
    float P[TN][HH];     // per-tile unnormalized attn / then l partials
    float logits[NN];
    float q[DD];
    float cur[DD];
    float hc[DD];        // heads concat
    float gt[DD];        // g~ (scaled by 1/sqrt(D))
    float redf[16];
    float redv[8];
    int   redi[8];
    float l[HH];
    float Mh[HH];
    float stat[2];
    unsigned char vis[NN];
    int   current;
    float Rb;
};

__global__ __launch_bounds__(512)
void decoder(const float* __restrict__ E, const float* __restrict__ Ws,
             const float* __restrict__ Wn, const float* __restrict__ fc,
             const float* __restrict__ Wog, const float* __restrict__ WkT,
             float* __restrict__ out_logp, float* __restrict__ out_seq, int T) {
    __shared__ SM sm;
    const int b = blockIdx.x;
    const int tid = threadIdx.x;
    const int lane = tid & 63;
    const int wv = tid >> 6;
    const float* Eb = E + (size_t)b * NN * DD;

    const int g4 = tid >> 7;          // 0..3  (quarter-group)
    const int d128 = tid & 127;
    const int n1 = tid >> 3, h1 = tid & 7;   // compat roles
    const int h2 = wv;                        // e-bar roles (wave == head)
    const int n3 = tid >> 3, g3 = tid & 7;    // logits roles

    // ---- init: visited, current, Rb = max_n ||E[n]|| ----
    sm.vis[tid] = 0;
    if (tid == 0) sm.current = 0;
    {
        float s = 0.f;
        const float4* row = (const float4*)(Eb + tid * DD);
        #pragma unroll 8
        for (int i = 0; i < 32; ++i) {
            float4 v = row[i];
            s += v.x * v.x + v.y * v.y + v.z * v.z + v.w * v.w;
        }
        for (int off = 1; off < 64; off <<= 1) s = fmaxf(s, __shfl_xor(s, off));
        if (lane == 0) sm.redf[wv] = s;
    }
    __syncthreads();
    if (tid == 0) {
        float m = sm.redf[0];
        for (int i = 1; i < 8; ++i) m = fmaxf(m, sm.redf[i]);
        sm.Rb = sqrtf(m);
    }
    __syncthreads();

    for (int t = 0; t < T; ++t) {
        // ================= phase 0: step context -> q =================
        int cu = sm.current;
        if (tid < DD) sm.cur[tid] = Eb[cu * DD + tid];
        __syncthreads();
        {
            float s = 0.f;
            int k0 = g4 * 32;
            #pragma unroll 8
            for (int k = k0; k < k0 + 32; ++k) s += sm.cur[k] * Ws[k * DD + d128];
            if (g4 == 3) s += ((float)t / (float)T) * Ws[128 * DD + d128];
            sm.part[g4][d128] = s;
        }
        __syncthreads();
        if (tid < DD)
            sm.q[tid] = fc[b * DD + tid] + sm.part[0][tid] + sm.part[1][tid]
                      + sm.part[2][tid] + sm.part[3][tid];
        __syncthreads();

        // ============ phase 0b: q~[h][d] (0.25 folded) + safe bound M ============
        {
            const int hA = g4, hB = g4 + 4;
            const float* WA = WkT + (hA * 16) * DD + d128;
            const float* WB = WkT + (hB * 16) * DD + d128;
            float a = 0.f, c = 0.f;
            #pragma unroll
            for (int j = 0; j < 16; ++j) {
                a += sm.q[hA * 16 + j] * WA[j * DD];
                c += sm.q[hB * 16 + j] * WB[j * DD];
            }
            a *= 0.25f; c *= 0.25f;
            sm.qt[hA][d128] = a;
            sm.qt[hB][d128] = c;
            float sa = a * a, sc = c * c;
            for (int off = 1; off < 64; off <<= 1) {
                sa += __shfl_xor(sa, off);
                sc += __shfl_xor(sc, off);
            }
            if (lane == 0) { sm.redf[wv] = sa; sm.redf[8 + wv] = sc; }
        }
        __syncthreads();
        if (tid < 8) {
            int h = tid;
            float ss = (h < 4) ? (sm.redf[2 * h] + sm.redf[2 * h + 1])
                               : (sm.redf[8 + 2 * (h - 4)] + sm.redf[8 + 2 * (h - 4) + 1]);
            sm.Mh[h] = sqrtf(ss) * sm.Rb;   // >= max_n compat[h,n] (Cauchy-Schwarz)
        }
        __syncthreads();

        // ===== phase 1: fused compat + exp + e-bar accumulate (single E pass) =====
        float eax = 0.f, eay = 0.f;   // e-bar accum: (h2, d = 2*lane, 2*lane+1)
        float l_priv = 0.f;
        for (int tile = 0; tile < NT; ++tile) {
            {   // stage 64 rows of E into LDS (coalesced)
                const float4* src = (const float4*)(Eb + tile * TN * DD);
                #pragma unroll
                for (int i = 0; i < 4; ++i) {
                    int c = tid + 512 * i;
                    int r = c >> 5, q4 = c & 31;
                    *(float4*)&sm.Et[r][q4 * 4] = src[r * 32 + q4];
                }
            }
            __syncthreads();
            {   // compat + exp: thread = (node n1, head h1)
                const float4* qr = (const float4*)sm.qt[h1];
                const float4* er = (const float4*)sm.Et[n1];
                float s0 = 0.f, s1 = 0.f, s2 = 0.f, s3 = 0.f;
                #pragma unroll
                for (int i = 0; i < 32; i += 4) {
                    float4 a0 = qr[i],     e0 = er[i];
                    float4 a1 = qr[i + 1], e1 = er[i + 1];
                    float4 a2 = qr[i + 2], e2 = er[i + 2];
                    float4 a3 = qr[i + 3], e3 = er[i + 3];
                    s0 += a0.x * e0.x + a0.y * e0.y + a0.z * e0.z + a0.w * e0.w;
                    s1 += a1.x * e1.x + a1.y * e1.y + a1.z * e1.z + a1.w * e1.w;
                    s2 += a2.x * e2.x + a2.y * e2.y + a2.z * e2.z + a2.w * e2.w;
                    s3 += a3.x * e3.x + a3.y * e3.y + a3.z * e3.z + a3.w * e3.w;
                }
                float cs = (s0 + s1) + (s2 + s3);
                int ng = tile * TN + n1;
                float p = sm.vis[ng] ? 0.0f : expf(cs - sm.Mh[h1]);
                sm.P[n1][h1] = p;
                l_priv += p;
            }
            __syncthreads();
            {   // e-bar accumulate: wave = head, lane covers 2 d's
                #pragma unroll 8
                for (int n = 0; n < TN; ++n) {
                    float pv = sm.P[n][h2];
                    float2 ev = *(const float2*)&sm.Et[n][2 * lane];
                    eax += pv * ev.x;
                    eay += pv * ev.y;
                }
            }
            __syncthreads();
        }
        // l reduce (reuse P)
        sm.P[n1][h1] = l_priv;
        __syncthreads();
        if (tid < 8) {
            float s = 0.f;
            for (int n = 0; n < TN; ++n) s += sm.P[n][tid];
            sm.l[tid] = s;
        }
        __syncthreads();
        {
            float inv = 1.0f / sm.l[h2];
            sm.eb[h2][2 * lane]     = eax * inv;
            sm.eb[h2][2 * lane + 1] = eay * inv;
        }
        __syncthreads();

        // ========= phase 2: heads = eb @ Wv ; g~ = heads @ W_og =========
        {
            float s = 0.f;
            int k0 = g4 * 32;
            const int hh = d128 >> 4;
            #pragma unroll 8
            for (int d = k0; d < k0 + 32; ++d)
                s += sm.eb[hh][d] * Wn[d * 384 + 128 + d128];
            sm.part[g4][d128] = s;
        }
        __syncthreads();
        if (tid < DD)
            sm.hc[tid] = sm.part[0][tid] + sm.part[1][tid] + sm.part[2][tid] + sm.part[3][tid];
        __syncthreads();
        {
            float s = 0.f;
            int k0 = g4 * 32;
            #pragma unroll 8
            for (int k = k0; k < k0 + 32; ++k)
                s += sm.hc[k] * Wog[k * DD + d128];
            sm.part[g4][d128] = s;
        }
        __syncthreads();
        if (tid < DD)
            sm.gt[tid] = (sm.part[0][tid] + sm.part[1][tid] + sm.part[2][tid]
                        + sm.part[3][tid]) * INV_SQRT_D;
        __syncthreads();

        // ========= phase 3: logits[n] = mask(10*tanh(g~ . E[n])) (2nd E pass) =========
        for (int tile = 0; tile < NT; ++tile) {
            {
                const float4* src = (const float4*)(Eb + tile * TN * DD);
                #pragma unroll
                for (int i = 0; i < 4; ++i) {
                    int c = tid + 512 * i;
                    int r = c >> 5, q4 = c & 31;
                    *(float4*)&sm.Et[r][q4 * 4] = src[r * 32 + q4];
                }
            }
            __syncthreads();
            {
                const float4* gr = (const float4*)(sm.gt + g3 * 16);
                const float4* er = (const float4*)(&sm.Et[n3][g3 * 16]);
                float s = 0.f;
                #pragma unroll
                for (int i = 0; i < 4; ++i) {
                    float4 a = gr[i], e = er[i];
                    s += a.x * e.x + a.y * e.y + a.z * e.z + a.w * e.w;
                }
                s += __shfl_xor(s, 1);
                s += __shfl_xor(s, 2);
                s += __shfl_xor(s, 4);
                if (g3 == 0) {
                    int ng = tile * TN + n3;
                    sm.logits[ng] = sm.vis[ng] ? NEGC : 10.0f * tanhf(s);
                }
            }
            __syncthreads();
        }

        // ========= phase 4: log_softmax, write, argmax(first-index ties), update =========
        {
            float x = sm.logits[tid];
            float m = x;
            for (int off = 1; off < 64; off <<= 1) m = fmaxf(m, __shfl_xor(m, off));
            if (lane == 0) sm.redf[wv] = m;
            __syncthreads();
            if (tid == 0) {
                float mm = sm.redf[0];
                for (int i = 1; i < 8; ++i) mm = fmaxf(mm, sm.redf[i]);
                sm.stat[0] = mm;
            }
            __syncthreads();
            float mm = sm.stat[0];
            float sh = x - mm;                 // masked: -1e9 - m -> rounds to -1e9
            float ex = expf(sh);               // masked: exactly 0
            float ssum = ex;
            for (int off = 1; off < 64; off <<= 1) ssum += __shfl_xor(ssum, off);
            if (lane == 0) sm.redf[wv] = ssum;
            __syncthreads();
            if (tid == 0) {
                float s8 = 0.f;
                for (int i = 0; i < 8; ++i) s8 += sm.redf[i];
                sm.stat[1] = logf(s8);
            }
            __syncthreads();
            float lse = sm.stat[1];
            float lp = sh - lse;
            out_logp[((size_t)b * T + t) * NN + tid] = lp;
            // argmax over stored log_p, lowest index wins ties (matches jnp.argmax)
            float bv = lp; int bi = tid;
            for (int off = 1; off < 64; off <<= 1) {
                float ov = __shfl_xor(bv, off);
                int   oi = __shfl_xor(bi, off);
                if (ov > bv || (ov == bv && oi < bi)) { bv = ov; bi = oi; }
            }
            if (lane == 0) { sm.redv[wv] = bv; sm.redi[wv] = bi; }
            __syncthreads();
            if (tid == 0) {
                float best = sm.redv[0]; int besti = sm.redi[0];
                for (int i = 1; i < 8; ++i) {
                    float ov = sm.redv[i]; int oi = sm.redi[i];
                    if (ov > best || (ov == best && oi < besti)) { best = ov; besti = oi; }
                }
                sm.vis[besti] = 1;
                sm.current = besti;
                out_seq[(size_t)b * T + t] = (float)besti;
            }
        }
        __syncthreads();
    }
}

// ------------------------------- launcher -----------------------------------
extern "C" void kernel_launch(void* const* d_in, const int* in_sizes, int n_in,
                              void* d_out, int out_size, void* d_ws, size_t ws_size,
                              hipStream_t stream) {
    const float* E    = (const float*)d_in[0];   // [B,N,D]
    const float* Wn   = (const float*)d_in[1];   // [D,3D]
    const float* Wf   = (const float*)d_in[2];   // [D,D]
    const float* Ws   = (const float*)d_in[3];   // [D+1,D]
    const float* Wout = (const float*)d_in[4];   // [D,D]
    float* out = (float*)d_out;

    const int T = out_size / (BB * (NN + 1));    // = num_steps (64)

    float* fc  = (float*)d_ws;                   // [B,D]
    float* Wog = fc + BB * DD;                   // [128,128]
    float* WkT = Wog + DD * DD;                  // [128,128]

    precompute_fc<<<BB, 128, 0, stream>>>(E, Wf, fc);
    precompute_w<<<DD, 128, 0, stream>>>(Wn, Wout, Wog, WkT);
    decoder<<<BB, 512, 0, stream>>>(E, Ws, Wn, fc, Wog, WkT,
                                    out, out + (size_t)BB * T * NN, T);
}